// Round 10
// baseline (1146.792 us; speedup 1.0000x reference)
//
#include <hip/hip_runtime.h>
#include <stdint.h>

// SpatiotemporalAttention: B=16 W=128 S=16 D=768 H=12 HD=64
//  LN1 -> GEMM qkv -> spatial attn (S=16) -> GEMM +resid(f32) -> xs2
//  LN2 -> GEMM tqkv -> temporal attn (W=128, causal, RoPE) -> GEMM +resid -> xt2
//  LN3 -> GEMM f1+gelu -> GEMM f2 +resid -> d_out (f32)
// R10 GEMM: 128x128, BK=32, 4 waves, ring-of-3 LDS slots (48 KB) -> 3 blocks/CU
// = 3 independent barrier domains, 3 waves/SIMD. 2 phases/tile, R4-proven
// stage/gate pattern (counted vmcnt(4), never 0 mid-loop). T1 XCD swizzle,
// T2 swizzle (4-chunk rows), T5 setprio.

#define NB 16
#define NW 128
#define NS 16
#define ND 768
#define NH 12
#define NTOK 32768

typedef __attribute__((ext_vector_type(8))) short short8;
typedef __attribute__((ext_vector_type(4))) float f32x4;

__device__ __forceinline__ float blo(unsigned v){ return __builtin_bit_cast(float, v << 16); }
__device__ __forceinline__ float bhi(unsigned v){ return __builtin_bit_cast(float, v & 0xffff0000u); }
__device__ __forceinline__ float bus(unsigned short u){ return __builtin_bit_cast(float, ((unsigned)u) << 16); }
__device__ __forceinline__ unsigned short f2b(float f){
  unsigned u = __builtin_bit_cast(unsigned, f);
  u += 0x7fffu + ((u >> 16) & 1u);
  return (unsigned short)(u >> 16);
}
__device__ __forceinline__ void gld_lds16(const void* g, void* l){
  __builtin_amdgcn_global_load_lds((const __attribute__((address_space(1))) void*)g,
                                   (__attribute__((address_space(3))) void*)l, 16, 0, 0);
}

// ---------------- weight convert f32 -> bf16 ----------------
__global__ __launch_bounds__(256) void convert_k(const float* __restrict__ in,
                                                 unsigned short* __restrict__ out, int n4){
  int i = blockIdx.x * 256 + threadIdx.x;
  int stride = gridDim.x * 256;
  for (; i < n4; i += stride){
    float4 v = ((const float4*)in)[i];
    unsigned lo = (unsigned)f2b(v.x) | ((unsigned)f2b(v.y) << 16);
    unsigned hi = (unsigned)f2b(v.z) | ((unsigned)f2b(v.w) << 16);
    ((uint2*)out)[i] = make_uint2(lo, hi);
  }
}

__global__ __launch_bounds__(256) void concat3_k(const float* __restrict__ a, const float* __restrict__ b,
                                                 const float* __restrict__ c, float* __restrict__ o){
  int i = blockIdx.x * 256 + threadIdx.x;
  if (i < 768){ o[i] = a[i]; o[768 + i] = b[i]; o[1536 + i] = c[i]; }
}

__global__ __launch_bounds__(256) void rope_k(float* __restrict__ tab){
  int i = blockIdx.x * 256 + threadIdx.x;
  if (i < 128 * 32){
    int w = i >> 5, p = i & 31;
    float inv = powf(10000.0f, -((float)(2 * p)) / 64.0f);
    float ang = (float)w * inv;
    tab[i * 2] = cosf(ang);
    tab[i * 2 + 1] = sinf(ang);
  }
}

// ---------------- LayerNorm ----------------
template<int INF32>
__global__ __launch_bounds__(256) void ln_k(const void* __restrict__ xin, const float* __restrict__ g,
                                            const float* __restrict__ bt, unsigned short* __restrict__ out){
  const int row = blockIdx.x;
  const int t = threadIdx.x;
  const float* xf = (const float*)xin;
  const unsigned short* xb = (const unsigned short*)xin;
  float v[3];
#pragma unroll
  for (int i = 0; i < 3; ++i){
    int j = t + i * 256;
    v[i] = INF32 ? xf[(size_t)row * 768 + j] : bus(xb[(size_t)row * 768 + j]);
  }
  float s = v[0] + v[1] + v[2];
  float ss = v[0]*v[0] + v[1]*v[1] + v[2]*v[2];
#pragma unroll
  for (int o = 1; o < 64; o <<= 1){ s += __shfl_xor(s, o, 64); ss += __shfl_xor(ss, o, 64); }
  __shared__ float red[8];
  int w = t >> 6;
  if ((t & 63) == 0){ red[w*2] = s; red[w*2+1] = ss; }
  __syncthreads();
  s = red[0] + red[2] + red[4] + red[6];
  ss = red[1] + red[3] + red[5] + red[7];
  float mean = s * (1.0f / 768.0f);
  float var = ss * (1.0f / 768.0f) - mean * mean;
  float rstd = rsqrtf(var + 1e-5f);
#pragma unroll
  for (int i = 0; i < 3; ++i){
    int j = t + i * 256;
    out[(size_t)row * 768 + j] = f2b((v[i] - mean) * rstd * g[j] + bt[j]);
  }
}

// ---------------- GEMM 128x128 / BK=32 / 4 waves / 2-phase / ring-3 / 3 blk/CU ----------------
// out[n][m] = sum_k A[n][k]*Bw[m][k] (+bias, +resid, gelu per MODE)
// MODE 0: bf16=acc+bias  1: bf16=gelu  2: +resid(f32)  3: +resid(bf16)  4: f32 out +resid(bf16)
//
// LDS: A/B each ring of 3 slots x 8KB (slot = 128 rows x 32 k bf16). 48 KB total
// -> 3 blocks/CU (3 independent barrier domains, 3 waves/SIMD: LDS-read of one
// block overlaps MFMA of another). Tile t lives in slot t%3.
// Phases per tile t:
//  p0 {rd b0,b1 + a0..a3 (6 ds_read_b128); stage A(t+2); bar; lgkm0; 8 MFMA (ni 0-1); bar}
//  p1 {rd b2,b3 (2);                       stage B(t+2); bar; lgkm0; 8 MFMA (ni 2-3);
//      gate vmcnt(4)|0; bar}
// Race proof (R4 pattern): tile-t reads drain at each phase's lgkm(0) before its
// trailing barrier; A/B(t+2) DMA targets slot (t+2)%3 (disjoint from t,t+1) and
// its slot's previous tenant (t-1) was fully read 2 barriers earlier. Gate
// vmcnt(4) leaves exactly A(t+2)+B(t+2) (4 loads) in flight -> A(t+1),B(t+1)
// landed before every wave's next-tile reads (which sit after gate+barrier).
// Tail: t+2>=NT -> vmcnt(0).
// T2 swizzle: row r (64B = 4 chunks of 16B) holds global chunk c at c^(r&3);
// pre-swizzled GLOBAL source (LDS dest linear, HW lane*16); reads XOR same.
// T1: bijective XCD y-band swizzle (all grids nwg%8==0).
template<int MODE>
__global__ __launch_bounds__(256, 3) void gemm128_k(const unsigned short* __restrict__ A,
                                                    const unsigned short* __restrict__ Bw,
                                                    const float* __restrict__ bias,
                                                    const void* __restrict__ resid,
                                                    void* __restrict__ outp, int K, int M){
  __shared__ char LB[49152];
  char* const Asl = LB;
  char* const Bsl = LB + 24576;
  const int tid = threadIdx.x;
  const int lane = tid & 63, w = tid >> 6;
  const int llo = lane & 15, lhi = lane >> 4;
  const int wm = w >> 1, wn = w & 1;
  const int NT = K >> 5;

  // T1 swizzle: contiguous y-band per XCD
  const int gx = gridDim.x;
  const int nwg = gx * gridDim.y;
  const int orig = blockIdx.y * gx + blockIdx.x;
  const int lin = (nwg & 7) ? orig : ((orig & 7) * (nwg >> 3) + (orig >> 3));
  const int by = lin / gx, bx = lin - by * gx;
  const int brow = by << 7;
  const int bcol = bx << 7;

  // staging: thread -> row r0=tid>>2 (0..63; +64 for 2nd load), chunk cp=tid&3
  const int r0 = tid >> 2, cp = tid & 3;
  const int swz = (cp << 4) ^ ((r0 & 3) << 4);
  const char* aG = (const char*)(A + (size_t)(brow + r0) * K) + swz;
  const char* bG = (const char*)(Bw + (size_t)(bcol + r0) * K) + swz;
  const int J2 = K * 128;             // 64-row step (bytes)
  const int ldst = w << 10;           // wave-uniform LDS base (HW adds lane*16)

  auto stage = [&](const char* g, int gb, char* slotbase){
    gld_lds16(g + gb,      slotbase + ldst);
    gld_lds16(g + gb + J2, slotbase + ldst + (1 << 12));
  };

  short8 a[4], b[4];
  auto rd_a = [&](const char* Ab){
#pragma unroll
    for (int mi = 0; mi < 4; ++mi){
      const int rr = (wm << 6) + (mi << 4) + llo;
      a[mi] = *(const short8*)(Ab + rr * 64 + ((lhi << 4) ^ ((rr & 3) << 4)));
    }
  };
  auto rd_b2 = [&](const char* Bb, int nb){
#pragma unroll
    for (int ni = 0; ni < 2; ++ni){
      const int cc = (wn << 6) + ((nb + ni) << 4) + llo;
      b[nb + ni] = *(const short8*)(Bb + cc * 64 + ((lhi << 4) ^ ((cc & 3) << 4)));
    }
  };

  f32x4 acc[4][4];
#pragma unroll
  for (int m = 0; m < 4; ++m)
#pragma unroll
    for (int n = 0; n < 4; ++n) acc[m][n] = f32x4{0.f, 0.f, 0.f, 0.f};

  auto mfma_h = [&](int nb){
    __builtin_amdgcn_s_setprio(1);
#pragma unroll
    for (int mi = 0; mi < 4; ++mi)
#pragma unroll
      for (int ni = 0; ni < 2; ++ni)
        acc[mi][nb + ni] = __builtin_amdgcn_mfma_f32_16x16x32_bf16(b[nb + ni], a[mi], acc[mi][nb + ni], 0, 0, 0);
    __builtin_amdgcn_s_setprio(0);
  };

  // prologue: A(0),B(0)->slot0; A(1),B(1)->slot1; vmcnt(4) leaves t=1 in flight
  stage(aG, 0,  Asl);
  stage(bG, 0,  Bsl);
  stage(aG, 64, Asl + 8192);
  stage(bG, 64, Bsl + 8192);
  asm volatile("s_waitcnt vmcnt(4)" ::: "memory");
  __builtin_amdgcn_s_barrier();

  int sl = 0;  // t % 3
  for (int t = 0; t < NT; ++t){
    const char* Ab = Asl + (sl << 13);
    const char* Bb = Bsl + (sl << 13);
    int sl2 = sl + 2; if (sl2 >= 3) sl2 -= 3;   // (t+2) % 3
    const int tb = t << 6;

    // ---- p0: rd b0,b1 + a0..3; stage A(t+2); mfma ni 0-1
    rd_b2(Bb, 0);
    rd_a(Ab);
    if (t + 2 < NT) stage(aG, tb + 128, Asl + (sl2 << 13));
    __builtin_amdgcn_s_barrier();
    asm volatile("s_waitcnt lgkmcnt(0)" ::: "memory");
    mfma_h(0);
    __builtin_amdgcn_s_barrier();

    // ---- p1: rd b2,b3; stage B(t+2); mfma ni 2-3; counted gate
    rd_b2(Bb, 2);
    if (t + 2 < NT) stage(bG, tb + 128, Bsl + (sl2 << 13));
    __builtin_amdgcn_s_barrier();
    asm volatile("s_waitcnt lgkmcnt(0)" ::: "memory");
    mfma_h(2);
    if (t + 2 < NT) asm volatile("s_waitcnt vmcnt(4)" ::: "memory");
    else            asm volatile("s_waitcnt vmcnt(0)" ::: "memory");
    __builtin_amdgcn_s_barrier();

    sl = sl + 1; if (sl >= 3) sl = 0;
  }

  // epilogue: lane holds 4 consecutive output COLUMNS per fragment
  const int orow = brow + (wm << 6);
  const int ocol = bcol + (wn << 6);
  const unsigned short* resb = (const unsigned short*)resid;
  const float* resf = (const float*)resid;
#pragma unroll
  for (int m = 0; m < 4; ++m){
    const int row = orow + (m << 4) + llo;
    const size_t rb = (size_t)row * M;
#pragma unroll
    for (int n = 0; n < 4; ++n){
      const int col = ocol + (n << 4) + (lhi << 2);
      const float4 bv = *(const float4*)&bias[col];
      float v0 = acc[m][n][0] + bv.x;
      float v1 = acc[m][n][1] + bv.y;
      float v2 = acc[m][n][2] + bv.z;
      float v3 = acc[m][n][3] + bv.w;
      const size_t off = rb + col;
      if (MODE == 1){
        float y0 = v0 * (1.5957691216f + 0.0713548163f * v0 * v0);
        float y1 = v1 * (1.5957691216f + 0.0713548163f * v1 * v1);
        float y2 = v2 * (1.5957691216f + 0.0713548163f * v2 * v2);
        float y3 = v3 * (1.5957691216f + 0.0713548163f * v3 * v3);
        v0 = v0 / (1.0f + __expf(-y0));
        v1 = v1 / (1.0f + __expf(-y1));
        v2 = v2 / (1.0f + __expf(-y2));
        v3 = v3 / (1.0f + __expf(-y3));
      } else if (MODE == 2){
        const float4 rv = *(const float4*)&resf[off];
        v0 += rv.x; v1 += rv.y; v2 += rv.z; v3 += rv.w;
      } else if (MODE == 3 || MODE == 4){
        const uint2 rv = *(const uint2*)&resb[off];
        v0 += blo(rv.x); v1 += bhi(rv.x); v2 += blo(rv.y); v3 += bhi(rv.y);
      }
      if (MODE == 4){
        float4 ov; ov.x = v0; ov.y = v1; ov.z = v2; ov.w = v3;
        *(float4*)&((float*)outp)[off] = ov;
      } else {
        unsigned lo = (unsigned)f2b(v0) | ((unsigned)f2b(v1) << 16);
        unsigned hi = (unsigned)f2b(v2) | ((unsigned)f2b(v3) << 16);
        *(uint2*)&((unsigned short*)outp)[off] = make_uint2(lo, hi);
      }
    }
  }
}

// ---------------- spatial attention: block = (bw, h), S=16, no mask ----------------
__global__ __launch_bounds__(256) void sattn_k(const unsigned short* __restrict__ qkv,
                                               unsigned short* __restrict__ o){
  const int bw = blockIdx.x, h = blockIdx.y;
  const int t = threadIdx.x;
  __shared__ unsigned short qh[16 * 68], kh[16 * 68], vh[16 * 68];
  __shared__ float pl[16 * 17];
  const int row = t >> 4, c4 = t & 15;
  const size_t base = ((size_t)(bw * 16 + row)) * 2304 + h * 64 + c4 * 4;
  *(uint2*)&qh[row * 68 + c4 * 4] = *(const uint2*)&qkv[base];
  *(uint2*)&kh[row * 68 + c4 * 4] = *(const uint2*)&qkv[base + 768];
  *(uint2*)&vh[row * 68 + c4 * 4] = *(const uint2*)&qkv[base + 1536];
  __syncthreads();

  const int q = row, k = c4;
  float s = 0.f;
#pragma unroll
  for (int c = 0; c < 16; ++c){
    uint2 qv = *(const uint2*)&qh[q * 68 + c * 4];
    uint2 kv = *(const uint2*)&kh[k * 68 + c * 4];
    s += blo(qv.x) * blo(kv.x) + bhi(qv.x) * bhi(kv.x);
    s += blo(qv.y) * blo(kv.y) + bhi(qv.y) * bhi(kv.y);
  }
  s *= 0.125f;
  float m = s;
#pragma unroll
  for (int off = 1; off < 16; off <<= 1) m = fmaxf(m, __shfl_xor(m, off, 64));
  float p = __expf(s - m);
  float su = p;
#pragma unroll
  for (int off = 1; off < 16; off <<= 1) su += __shfl_xor(su, off, 64);
  pl[q * 17 + k] = p / su;
  __syncthreads();

  float o0 = 0.f, o1 = 0.f, o2 = 0.f, o3 = 0.f;
#pragma unroll
  for (int kk = 0; kk < 16; ++kk){
    float pw = pl[q * 17 + kk];
    uint2 vv = *(const uint2*)&vh[kk * 68 + c4 * 4];
    o0 += pw * blo(vv.x); o1 += pw * bhi(vv.x);
    o2 += pw * blo(vv.y); o3 += pw * bhi(vv.y);
  }
  const size_t ob = ((size_t)(bw * 16 + q)) * 768 + h * 64 + c4 * 4;
  unsigned r0 = (unsigned)f2b(o0) | ((unsigned)f2b(o1) << 16);
  unsigned r1 = (unsigned)f2b(o2) | ((unsigned)f2b(o3) << 16);
  *(uint2*)&o[ob] = make_uint2(r0, r1);
}

// ---------------- temporal attention: block = (b*16+s, h), W=128, causal, RoPE ----------------
__global__ __launch_bounds__(256) void tattn_k(const unsigned short* __restrict__ qkv,
                                               const float* __restrict__ rope,
                                               unsigned short* __restrict__ o){
  const int bs = blockIdx.x, h = blockIdx.y;
  const int b = bs >> 4, s = bs & 15;
  const int t = threadIdx.x, lane = t & 63, w = t >> 6;
  const int lhi = lane >> 4, llo = lane & 15;
  __shared__ unsigned short Qs[128 * 64];
  __shared__ unsigned short Ks[128 * 64];
  __shared__ unsigned short Vt[64 * 128];
  __shared__ unsigned short P[128 * 128];

  {
    const int r = t >> 1;
    const int dbase = (t & 1) * 32;
    const size_t tokb = ((size_t)((b * 128 + r) * 16 + s)) * 2304 + h * 64;
    const float2* rp = (const float2*)rope;
#pragma unroll
    for (int mch = 0; mch < 4; ++mch){
      const int d0 = dbase + mch * 8;
      uint4 qv = *(const uint4*)&qkv[tokb + d0];
      uint4 kv = *(const uint4*)&qkv[tokb + 768 + d0];
      uint4 vv = *(const uint4*)&qkv[tokb + 1536 + d0];
      unsigned qin[4] = {qv.x, qv.y, qv.z, qv.w};
      unsigned kin[4] = {kv.x, kv.y, kv.z, kv.w};
      unsigned qo[4], ko[4];
#pragma unroll
      for (int j = 0; j < 4; ++j){
        float2 cssn = rp[r * 32 + (d0 >> 1) + j];
        float cs = cssn.x, sn = cssn.y;
        float qe = blo(qin[j]), qd = bhi(qin[j]);
        float ke = blo(kin[j]), kd = bhi(kin[j]);
        qo[j] = (unsigned)f2b(qe * cs - qd * sn) | ((unsigned)f2b(qe * sn + qd * cs) << 16);
        ko[j] = (unsigned)f2b(ke * cs - kd * sn) | ((unsigned)f2b(ke * sn + kd * cs) << 16);
      }
      const int byq = r * 128 + ((d0 * 2) ^ ((r & 7) << 4));
      *(uint4*)((char*)Qs + byq) = make_uint4(qo[0], qo[1], qo[2], qo[3]);
      *(uint4*)((char*)Ks + byq) = make_uint4(ko[0], ko[1], ko[2], ko[3]);
      unsigned vin[4] = {vv.x, vv.y, vv.z, vv.w};
#pragma unroll
      for (int j = 0; j < 8; ++j){
        const int d = d0 + j;
        unsigned short val = (j & 1) ? (unsigned short)(vin[j >> 1] >> 16)
                                     : (unsigned short)(vin[j >> 1] & 0xffffu);
        *(unsigned short*)((char*)Vt + d * 256 + ((r * 2) ^ ((d & 7) << 4))) = val;
      }
    }
  }
  __syncthreads();

  const int qbase = w * 32;
  f32x4 st[8][2];
#pragma unroll
  for (int i = 0; i < 8; ++i){ st[i][0] = f32x4{0.f,0.f,0.f,0.f}; st[i][1] = f32x4{0.f,0.f,0.f,0.f}; }
#pragma unroll
  for (int kd = 0; kd < 2; ++kd){
    short8 bq[2];
#pragma unroll
    for (int fq = 0; fq < 2; ++fq){
      const int qr = qbase + fq * 16 + llo;
      bq[fq] = *(const short8*)((const char*)Qs + qr * 128 + ((kd * 64 + lhi * 16) ^ ((qr & 7) << 4)));
    }
#pragma unroll
    for (int fk = 0; fk < 8; ++fk){
      const int kr = fk * 16 + llo;
      short8 ak = *(const short8*)((const char*)Ks + kr * 128 + ((kd * 64 + lhi * 16) ^ ((kr & 7) << 4)));
      st[fk][0] = __builtin_amdgcn_mfma_f32_16x16x32_bf16(ak, bq[0], st[fk][0], 0, 0, 0);
      st[fk][1] = __builtin_amdgcn_mfma_f32_16x16x32_bf16(ak, bq[1], st[fk][1], 0, 0, 0);
    }
  }

#pragma unroll
  for (int fq = 0; fq < 2; ++fq){
    const int qg = qbase + fq * 16 + llo;
    float m = -1e30f;
#pragma unroll
    for (int fk = 0; fk < 8; ++fk)
#pragma unroll
      for (int rr = 0; rr < 4; ++rr){
        const int kg = fk * 16 + lhi * 4 + rr;
        float sv = (kg <= qg) ? st[fk][fq][rr] : -1e30f;
        st[fk][fq][rr] = sv;
        m = fmaxf(m, sv);
      }
    m = fmaxf(m, __shfl_xor(m, 16, 64));
    m = fmaxf(m, __shfl_xor(m, 32, 64));
    float su = 0.f;
#pragma unroll
    for (int fk = 0; fk < 8; ++fk)
#pragma unroll
      for (int rr = 0; rr < 4; ++rr){
        float p = __expf((st[fk][fq][rr] - m) * 0.125f);
        st[fk][fq][rr] = p;
        su += p;
      }
    su += __shfl_xor(su, 16, 64);
    su += __shfl_xor(su, 32, 64);
    const float rs = 1.0f / su;
#pragma unroll
    for (int fk = 0; fk < 8; ++fk){
      const int kk = fk * 16 + lhi * 4;
      unsigned lo = (unsigned)f2b(st[fk][fq][0] * rs) | ((unsigned)f2b(st[fk][fq][1] * rs) << 16);
      unsigned hi = (unsigned)f2b(st[fk][fq][2] * rs) | ((unsigned)f2b(st[fk][fq][3] * rs) << 16);
      *(uint2*)((char*)P + qg * 256 + ((kk * 2) ^ ((qg & 7) << 4))) = make_uint2(lo, hi);
    }
  }
  __syncthreads();

  f32x4 oacc[2][4];
#pragma unroll
  for (int i = 0; i < 2; ++i)
#pragma unroll
    for (int j = 0; j < 4; ++j) oacc[i][j] = f32x4{0.f,0.f,0.f,0.f};
#pragma unroll
  for (int ks = 0; ks < 4; ++ks){
    short8 pa[2];
#pragma unroll
    for (int fq = 0; fq < 2; ++fq){
      const int qr = qbase + fq * 16 + llo;
      pa[fq] = *(const short8*)((const char*)P + qr * 256 + ((ks * 64 + lhi * 16) ^ ((qr & 7) << 4)));
    }
#pragma unroll
    for (int fd = 0; fd < 4; ++fd){
      const int dr = fd * 16 + llo;
      short8 vb = *(const short8*)((const char*)Vt + dr * 256 + ((ks * 64 + lhi * 16) ^ ((dr & 7) << 4)));
      oacc[0][fd] = __builtin_amdgcn_mfma_f32_16x16x32_bf16(pa[0], vb, oacc[0][fd], 0, 0, 0);
      oacc[1][fd] = __builtin_amdgcn_mfma_f32_16x16x32_bf16(pa[1], vb, oacc[1][fd], 0, 0, 0);
    }
  }

#pragma unroll
  for (int fq = 0; fq < 2; ++fq)
#pragma unroll
    for (int fd = 0; fd < 4; ++fd)
#pragma unroll
      for (int rr = 0; rr < 4; ++rr){
        const int qg = qbase + fq * 16 + lhi * 4 + rr;
        const int d = fd * 16 + llo;
        const size_t ob = ((size_t)((b * 128 + qg) * 16 + s)) * 768 + h * 64 + d;
        o[ob] = f2b(oacc[fq][fd][rr]);
      }
}

__global__ __launch_bounds__(256) void sentinel_k(float* out){
  if (blockIdx.x == 0 && threadIdx.x == 0) out[0] = 12345.0f;
}

// ---------------- launch ----------------
extern "C" void kernel_launch(void* const* d_in, const int* in_sizes, int n_in,
                              void* d_out, int out_size, void* d_ws, size_t ws_size,
                              hipStream_t stream){
  const float* x       = (const float*)d_in[0];
  const float* sn_g    = (const float*)d_in[2];
  const float* sn_b    = (const float*)d_in[3];
  const float* sa_in_w = (const float*)d_in[4];
  const float* sa_in_b = (const float*)d_in[5];
  const float* sa_out_w= (const float*)d_in[6];
  const float* sa_out_b= (const float*)d_in[7];
  const float* tn_g    = (const float*)d_in[8];
  const float* tn_b    = (const float*)d_in[9];
  const float* tq_w    = (const float*)d_in[10];
  const float* tq_b    = (const float*)d_in[11];
  const float* tk_w    = (const float*)d_in[12];
  const float* tk_b    = (const float*)d_in[13];
  const float* tv_w    = (const float*)d_in[14];
  const float* tv_b    = (const float*)d_in[15];
  const float* to_w    = (const float*)d_in[16];
  const float* to_b    = (const float*)d_in[17];
  const float* fn_g    = (const float*)d_in[18];
  const float* fn_b    = (const float*)d_in[19];
  const float* f1_w    = (const float*)d_in[20];
  const float* f1_b    = (const float*)d_in[21];
  const float* f2_w    = (const float*)d_in[22];
  const float* f2_b    = (const float*)d_in[23];

  char* ws = (char*)d_ws;
  size_t off = 0;
  auto alloc = [&](size_t bytes) -> void* {
    void* p = ws + off;
    off += (bytes + 255) & ~(size_t)255;
    return p;
  };
  unsigned short* Wqkv = (unsigned short*)alloc((size_t)2304*768*2);
  unsigned short* Wo1  = (unsigned short*)alloc((size_t)768*768*2);
  unsigned short* W3   = (unsigned short*)alloc((size_t)2304*768*2);
  float*          b3   = (float*)alloc(2304*4);
  unsigned short* Wto  = (unsigned short*)alloc((size_t)768*768*2);
  unsigned short* Wf1  = (unsigned short*)alloc((size_t)3072*768*2);
  unsigned short* Wf2  = (unsigned short*)alloc((size_t)768*3072*2);
  float*          rope = (float*)alloc(128*32*2*4);
  unsigned short* xn   = (unsigned short*)alloc((size_t)NTOK*768*2);
  unsigned short* qkv  = (unsigned short*)alloc((size_t)NTOK*3072*2);
  unsigned short* xs2  = (unsigned short*)alloc((size_t)NTOK*768*2);
  unsigned short* xt2  = (unsigned short*)alloc((size_t)NTOK*768*2);
  unsigned short* ob   = xn; // alias: xn dead when attn output written

  if (ws_size < off){ sentinel_k<<<1, 64, 0, stream>>>((float*)d_out); return; }

  convert_k<<<1024, 256, 0, stream>>>(sa_in_w, Wqkv, 2304*768/4);
  convert_k<<<512, 256, 0, stream>>>(sa_out_w, Wo1, 768*768/4);
  convert_k<<<512, 256, 0, stream>>>(tq_w, W3, 768*768/4);
  convert_k<<<512, 256, 0, stream>>>(tk_w, W3 + 768*768, 768*768/4);
  convert_k<<<512, 256, 0, stream>>>(tv_w, W3 + 2*768*768, 768*768/4);
  concat3_k<<<3, 256, 0, stream>>>(tq_b, tk_b, tv_b, b3);
  convert_k<<<512, 256, 0, stream>>>(to_w, Wto, 768*768/4);
  convert_k<<<1024, 256, 0, stream>>>(f1_w, Wf1, 3072*768/4);
  convert_k<<<1024, 256, 0, stream>>>(f2_w, Wf2, 768*3072/4);
  rope_k<<<16, 256, 0, stream>>>(rope);

  // spatial block
  ln_k<1><<<NTOK, 256, 0, stream>>>(x, sn_g, sn_b, xn);
  gemm128_k<0><<<dim3(18, 256), 256, 0, stream>>>(xn, Wqkv, sa_in_b, nullptr, qkv, 768, 2304);
  sattn_k<<<dim3(2048, 12), 256, 0, stream>>>(qkv, ob);
  gemm128_k<2><<<dim3(6, 256), 256, 0, stream>>>(ob, Wo1, sa_out_b, x, xs2, 768, 768);

  // temporal block
  ln_k<0><<<NTOK, 256, 0, stream>>>(xs2, tn_g, tn_b, xn);
  gemm128_k<0><<<dim3(18, 256), 256, 0, stream>>>(xn, W3, b3, nullptr, qkv, 768, 2304);
  tattn_k<<<dim3(256, 12), 256, 0, stream>>>(qkv, rope, ob);
  gemm128_k<3><<<dim3(6, 256), 256, 0, stream>>>(ob, Wto, to_b, xs2, xt2, 768, 768);

  // FFN
  ln_k<0><<<NTOK, 256, 0, stream>>>(xt2, fn_g, fn_b, xn);
  gemm128_k<1><<<dim3(24, 256), 256, 0, stream>>>(xn, Wf1, f1_b, nullptr, qkv, 768, 3072);
  gemm128_k<4><<<dim3(6, 256), 256, 0, stream>>>(qkv, Wf2, f2_b, xt2, d_out, 3072, 768);
}

// Round 11
// 1110.787 us; speedup vs baseline: 1.0324x; 1.0324x over previous
//
#include <hip/hip_runtime.h>
#include <stdint.h>

// SpatiotemporalAttention: B=16 W=128 S=16 D=768 H=12 HD=64
//  LN1 -> GEMM qkv -> spatial attn (S=16) -> GEMM +resid(f32) -> xs2
//  LN2 -> GEMM tqkv -> temporal attn (W=128, causal, RoPE) -> GEMM +resid -> xt2
//  LN3 -> GEMM f1+gelu -> GEMM f2 +resid -> d_out (f32)
// R11 GEMM: m97-faithful. 128x128, BK=32, 4 waves, SINGLE-buffered 16KB LDS
// (4-5 blocks/CU = 4-5 independent barrier domains), 2 barriers/K-step,
// hoisted loop-invariant ds_read offsets, 2-way-free LDS swizzle
// (2 rows/128B line, pos=((r&1)*4|kc)^(line&7)), L2-grouped XCD swizzle.

#define NB 16
#define NW 128
#define NS 16
#define ND 768
#define NH 12
#define NTOK 32768

typedef __attribute__((ext_vector_type(8))) short short8;
typedef __attribute__((ext_vector_type(4))) float f32x4;

__device__ __forceinline__ float blo(unsigned v){ return __builtin_bit_cast(float, v << 16); }
__device__ __forceinline__ float bhi(unsigned v){ return __builtin_bit_cast(float, v & 0xffff0000u); }
__device__ __forceinline__ float bus(unsigned short u){ return __builtin_bit_cast(float, ((unsigned)u) << 16); }
__device__ __forceinline__ unsigned short f2b(float f){
  unsigned u = __builtin_bit_cast(unsigned, f);
  u += 0x7fffu + ((u >> 16) & 1u);
  return (unsigned short)(u >> 16);
}
__device__ __forceinline__ void gld_lds16(const void* g, void* l){
  __builtin_amdgcn_global_load_lds((const __attribute__((address_space(1))) void*)g,
                                   (__attribute__((address_space(3))) void*)l, 16, 0, 0);
}

// ---------------- merged weight convert f32 -> bf16 (8 segments, 1 launch) ----------------
__global__ __launch_bounds__(256) void convertall_k(
    const float* __restrict__ s0, const float* __restrict__ s1, const float* __restrict__ s2,
    const float* __restrict__ s3, const float* __restrict__ s4, const float* __restrict__ s5,
    const float* __restrict__ s6, const float* __restrict__ s7,
    unsigned short* __restrict__ d0, unsigned short* __restrict__ d1, unsigned short* __restrict__ d2,
    unsigned short* __restrict__ d3, unsigned short* __restrict__ d4, unsigned short* __restrict__ d5,
    unsigned short* __restrict__ d6, unsigned short* __restrict__ d7){
  // sizes in float4 units
  const int n0 = 442368, n1 = 147456, n2 = 147456, n3 = 147456, n4 = 147456, n5 = 147456, n6 = 589824, n7 = 589824;
  const int c0 = n0, c1 = c0+n1, c2 = c1+n2, c3 = c2+n3, c4 = c3+n4, c5 = c4+n5, c6 = c5+n6, c7 = c6+n7;
  int i = blockIdx.x * 256 + threadIdx.x;
  const int stride = gridDim.x * 256;
  for (; i < c7; i += stride){
    const float* s; unsigned short* d; int j;
    if      (i < c0){ s = s0; d = d0; j = i; }
    else if (i < c1){ s = s1; d = d1; j = i - c0; }
    else if (i < c2){ s = s2; d = d2; j = i - c1; }
    else if (i < c3){ s = s3; d = d3; j = i - c2; }
    else if (i < c4){ s = s4; d = d4; j = i - c3; }
    else if (i < c5){ s = s5; d = d5; j = i - c4; }
    else if (i < c6){ s = s6; d = d6; j = i - c5; }
    else            { s = s7; d = d7; j = i - c6; }
    float4 v = ((const float4*)s)[j];
    unsigned lo = (unsigned)f2b(v.x) | ((unsigned)f2b(v.y) << 16);
    unsigned hi = (unsigned)f2b(v.z) | ((unsigned)f2b(v.w) << 16);
    ((uint2*)d)[j] = make_uint2(lo, hi);
  }
}

__global__ __launch_bounds__(256) void concat3_k(const float* __restrict__ a, const float* __restrict__ b,
                                                 const float* __restrict__ c, float* __restrict__ o){
  int i = blockIdx.x * 256 + threadIdx.x;
  if (i < 768){ o[i] = a[i]; o[768 + i] = b[i]; o[1536 + i] = c[i]; }
}

__global__ __launch_bounds__(256) void rope_k(float* __restrict__ tab){
  int i = blockIdx.x * 256 + threadIdx.x;
  if (i < 128 * 32){
    int w = i >> 5, p = i & 31;
    float inv = powf(10000.0f, -((float)(2 * p)) / 64.0f);
    float ang = (float)w * inv;
    tab[i * 2] = cosf(ang);
    tab[i * 2 + 1] = sinf(ang);
  }
}

// ---------------- LayerNorm ----------------
template<int INF32>
__global__ __launch_bounds__(256) void ln_k(const void* __restrict__ xin, const float* __restrict__ g,
                                            const float* __restrict__ bt, unsigned short* __restrict__ out){
  const int row = blockIdx.x;
  const int t = threadIdx.x;
  const float* xf = (const float*)xin;
  const unsigned short* xb = (const unsigned short*)xin;
  float v[3];
#pragma unroll
  for (int i = 0; i < 3; ++i){
    int j = t + i * 256;
    v[i] = INF32 ? xf[(size_t)row * 768 + j] : bus(xb[(size_t)row * 768 + j]);
  }
  float s = v[0] + v[1] + v[2];
  float ss = v[0]*v[0] + v[1]*v[1] + v[2]*v[2];
#pragma unroll
  for (int o = 1; o < 64; o <<= 1){ s += __shfl_xor(s, o, 64); ss += __shfl_xor(ss, o, 64); }
  __shared__ float red[8];
  int w = t >> 6;
  if ((t & 63) == 0){ red[w*2] = s; red[w*2+1] = ss; }
  __syncthreads();
  s = red[0] + red[2] + red[4] + red[6];
  ss = red[1] + red[3] + red[5] + red[7];
  float mean = s * (1.0f / 768.0f);
  float var = ss * (1.0f / 768.0f) - mean * mean;
  float rstd = rsqrtf(var + 1e-5f);
#pragma unroll
  for (int i = 0; i < 3; ++i){
    int j = t + i * 256;
    out[(size_t)row * 768 + j] = f2b((v[i] - mean) * rstd * g[j] + bt[j]);
  }
}

// ---------------- GEMM m97-style: 128x128 / BK=32 / 4 waves / single-buffer ----------------
// out[n][m] = sum_k A[n][k]*Bw[m][k] (+bias, +resid, gelu per MODE)
// MODE 0: bf16=acc+bias  1: bf16=gelu  2: +resid(f32)  3: +resid(bf16)  4: f32 out +resid(bf16)
//
// LDS: As/Bs 8KB each (tile = 128 rows x 32 k bf16), packed 2 rows per 128B
// line: row r, kchunk kc (16B) stored at line=r>>1, pos = (((r&1)<<2)|kc) ^
// (line&7). Quarter-wave bank audit: 8 slots x 2 lanes = 2-way = free (m136;
// matches R8's measured-0 pattern). Staged with linear LDS dest + pre-swizzled
// per-lane GLOBAL source (rule #21). Read offsets are LOOP-INVARIANT (single
// buffer) -> zero per-iter address VALU; stage pointers advance by 64B.
// K-loop: {stage(4 gld_lds); __syncthreads (vmcnt0 drain); 8 ds_read + 16 MFMA;
// __syncthreads}. Latency hidden by 4-5 co-resident blocks (16KB LDS,
// launch_bounds(256,4)) - independent barrier domains.
// T1+L2 grouping: XCD gets contiguous y-band; within band, groups of 8
// row-blocks sweep all bx (A group ~1.6MB L2-resident; B streams from L3).
template<int MODE>
__global__ __launch_bounds__(256, 4) void gemm97_k(const unsigned short* __restrict__ A,
                                                   const unsigned short* __restrict__ Bw,
                                                   const float* __restrict__ bias,
                                                   const void* __restrict__ resid,
                                                   void* __restrict__ outp, int K, int M){
  __shared__ char LB[16384];
  char* const As = LB;
  char* const Bs = LB + 8192;
  const int tid = threadIdx.x;
  const int lane = tid & 63, w = tid >> 6;
  const int llo = lane & 15, lhi = lane >> 4;
  const int wm = w >> 1, wn = w & 1;
  const int NT = K >> 5;

  // T1: XCD band + 8-row groups sweeping bx
  const int gx = gridDim.x, gy = gridDim.y;
  const int nwg = gx * gy;
  const int orig = blockIdx.y * gx + blockIdx.x;
  int bxx, byy;
  if (((nwg & 7) == 0) && ((gy & 63) == 0)){
    const int xcd = orig & 7, idx = orig >> 3;
    const int grpsz = gx << 3;
    const int g = idx / grpsz, rem = idx - g * grpsz;
    bxx = rem >> 3;
    byy = xcd * (gy >> 3) + (g << 3) + (rem & 7);
  } else {
    byy = orig / gx; bxx = orig - byy * gx;
  }
  const int brow = byy << 7;
  const int bcol = bxx << 7;

  // staging source map: thread -> (line=tid>>3, cf=tid&7); cfs = cf^(line&7);
  // row = 2*line + (cfs>>2), kc = cfs&3. Dest linear tid*16 (+4096 for j=1).
  const int lineb = tid >> 3, cfb = tid & 7;
  const int cfs = cfb ^ (lineb & 7);
  const int srow = 2 * lineb + (cfs >> 2);
  const int skc = cfs & 3;
  const char* pa = (const char*)(A + (size_t)(brow + srow) * K + skc * 8);
  const char* pb = (const char*)(Bw + (size_t)(bcol + srow) * K + skc * 8);
  const int rowJ = K * 128;          // +64 rows in bytes
  const int ldst = w << 10;          // wave-uniform LDS base (HW adds lane*16)

  // loop-invariant read byte-offsets
  int aoff[4], boff[4];
#pragma unroll
  for (int mi = 0; mi < 4; ++mi){
    const int rr = (wm << 6) + (mi << 4) + llo;
    const int line = rr >> 1;
    const int pos = ((((rr & 1) << 2) | lhi)) ^ (line & 7);
    aoff[mi] = line * 128 + pos * 16;
  }
#pragma unroll
  for (int ni = 0; ni < 4; ++ni){
    const int cc = (wn << 6) + (ni << 4) + llo;
    const int line = cc >> 1;
    const int pos = ((((cc & 1) << 2) | lhi)) ^ (line & 7);
    boff[ni] = line * 128 + pos * 16;
  }

  f32x4 acc[4][4];
#pragma unroll
  for (int m = 0; m < 4; ++m)
#pragma unroll
    for (int n = 0; n < 4; ++n) acc[m][n] = f32x4{0.f, 0.f, 0.f, 0.f};

  for (int t = 0; t < NT; ++t){
    gld_lds16(pa,        As + ldst);
    gld_lds16(pa + rowJ, As + ldst + 4096);
    gld_lds16(pb,        Bs + ldst);
    gld_lds16(pb + rowJ, Bs + ldst + 4096);
    pa += 64; pb += 64;
    __syncthreads();   // drains vmcnt(0): tile ready
    short8 a[4], b[4];
#pragma unroll
    for (int i = 0; i < 4; ++i){
      a[i] = *(const short8*)(As + aoff[i]);
      b[i] = *(const short8*)(Bs + boff[i]);
    }
    __builtin_amdgcn_s_setprio(1);
#pragma unroll
    for (int mi = 0; mi < 4; ++mi)
#pragma unroll
      for (int ni = 0; ni < 4; ++ni)
        acc[mi][ni] = __builtin_amdgcn_mfma_f32_16x16x32_bf16(b[ni], a[mi], acc[mi][ni], 0, 0, 0);
    __builtin_amdgcn_s_setprio(0);
    __syncthreads();
  }

  // epilogue: lane holds 4 consecutive output COLUMNS per fragment
  const int orow = brow + (wm << 6);
  const int ocol = bcol + (wn << 6);
  const unsigned short* resb = (const unsigned short*)resid;
  const float* resf = (const float*)resid;
#pragma unroll
  for (int m = 0; m < 4; ++m){
    const int row = orow + (m << 4) + llo;
    const size_t rb = (size_t)row * M;
#pragma unroll
    for (int n = 0; n < 4; ++n){
      const int col = ocol + (n << 4) + (lhi << 2);
      const float4 bv = *(const float4*)&bias[col];
      float v0 = acc[m][n][0] + bv.x;
      float v1 = acc[m][n][1] + bv.y;
      float v2 = acc[m][n][2] + bv.z;
      float v3 = acc[m][n][3] + bv.w;
      const size_t off = rb + col;
      if (MODE == 1){
        float y0 = v0 * (1.5957691216f + 0.0713548163f * v0 * v0);
        float y1 = v1 * (1.5957691216f + 0.0713548163f * v1 * v1);
        float y2 = v2 * (1.5957691216f + 0.0713548163f * v2 * v2);
        float y3 = v3 * (1.5957691216f + 0.0713548163f * v3 * v3);
        v0 = v0 / (1.0f + __expf(-y0));
        v1 = v1 / (1.0f + __expf(-y1));
        v2 = v2 / (1.0f + __expf(-y2));
        v3 = v3 / (1.0f + __expf(-y3));
      } else if (MODE == 2){
        const float4 rv = *(const float4*)&resf[off];
        v0 += rv.x; v1 += rv.y; v2 += rv.z; v3 += rv.w;
      } else if (MODE == 3 || MODE == 4){
        const uint2 rv = *(const uint2*)&resb[off];
        v0 += blo(rv.x); v1 += bhi(rv.x); v2 += blo(rv.y); v3 += bhi(rv.y);
      }
      if (MODE == 4){
        float4 ov; ov.x = v0; ov.y = v1; ov.z = v2; ov.w = v3;
        *(float4*)&((float*)outp)[off] = ov;
      } else {
        unsigned lo = (unsigned)f2b(v0) | ((unsigned)f2b(v1) << 16);
        unsigned hi = (unsigned)f2b(v2) | ((unsigned)f2b(v3) << 16);
        *(uint2*)&((unsigned short*)outp)[off] = make_uint2(lo, hi);
      }
    }
  }
}

// ---------------- spatial attention: block = (bw, h), S=16, no mask ----------------
__global__ __launch_bounds__(256) void sattn_k(const unsigned short* __restrict__ qkv,
                                               unsigned short* __restrict__ o){
  const int bw = blockIdx.x, h = blockIdx.y;
  const int t = threadIdx.x;
  __shared__ unsigned short qh[16 * 68], kh[16 * 68], vh[16 * 68];
  __shared__ float pl[16 * 17];
  const int row = t >> 4, c4 = t & 15;
  const size_t base = ((size_t)(bw * 16 + row)) * 2304 + h * 64 + c4 * 4;
  *(uint2*)&qh[row * 68 + c4 * 4] = *(const uint2*)&qkv[base];
  *(uint2*)&kh[row * 68 + c4 * 4] = *(const uint2*)&qkv[base + 768];
  *(uint2*)&vh[row * 68 + c4 * 4] = *(const uint2*)&qkv[base + 1536];
  __syncthreads();

  const int q = row, k = c4;
  float s = 0.f;
#pragma unroll
  for (int c = 0; c < 16; ++c){
    uint2 qv = *(const uint2*)&qh[q * 68 + c * 4];
    uint2 kv = *(const uint2*)&kh[k * 68 + c * 4];
    s += blo(qv.x) * blo(kv.x) + bhi(qv.x) * bhi(kv.x);
    s += blo(qv.y) * blo(kv.y) + bhi(qv.y) * bhi(kv.y);
  }
  s *= 0.125f;
  float m = s;
#pragma unroll
  for (int off = 1; off < 16; off <<= 1) m = fmaxf(m, __shfl_xor(m, off, 64));
  float p = __expf(s - m);
  float su = p;
#pragma unroll
  for (int off = 1; off < 16; off <<= 1) su += __shfl_xor(su, off, 64);
  pl[q * 17 + k] = p / su;
  __syncthreads();

  float o0 = 0.f, o1 = 0.f, o2 = 0.f, o3 = 0.f;
#pragma unroll
  for (int kk = 0; kk < 16; ++kk){
    float pw = pl[q * 17 + kk];
    uint2 vv = *(const uint2*)&vh[kk * 68 + c4 * 4];
    o0 += pw * blo(vv.x); o1 += pw * bhi(vv.x);
    o2 += pw * blo(vv.y); o3 += pw * bhi(vv.y);
  }
  const size_t ob = ((size_t)(bw * 16 + q)) * 768 + h * 64 + c4 * 4;
  unsigned r0 = (unsigned)f2b(o0) | ((unsigned)f2b(o1) << 16);
  unsigned r1 = (unsigned)f2b(o2) | ((unsigned)f2b(o3) << 16);
  *(uint2*)&o[ob] = make_uint2(r0, r1);
}

// ---------------- temporal attention: block = (b*16+s, h), W=128, causal, RoPE ----------------
__global__ __launch_bounds__(256) void tattn_k(const unsigned short* __restrict__ qkv,
                                               const float* __restrict__ rope,
                                               unsigned short* __restrict__ o){
  const int bs = blockIdx.x, h = blockIdx.y;
  const int b = bs >> 4, s = bs & 15;
  const int t = threadIdx.x, lane = t & 63, w = t >> 6;
  const int lhi = lane >> 4, llo = lane & 15;
  __shared__ unsigned short Qs[128 * 64];
  __shared__ unsigned short Ks[128 * 64];
  __shared__ unsigned short Vt[64 * 128];
  __shared__ unsigned short P[128 * 128];

  {
    const int r = t >> 1;
    const int dbase = (t & 1) * 32;
    const size_t tokb = ((size_t)((b * 128 + r) * 16 + s)) * 2304 + h * 64;
    const float2* rp = (const float2*)rope;
#pragma unroll
    for (int mch = 0; mch < 4; ++mch){
      const int d0 = dbase + mch * 8;
      uint4 qv = *(const uint4*)&qkv[tokb + d0];
      uint4 kv = *(const uint4*)&qkv[tokb + 768 + d0];
      uint4 vv = *(const uint4*)&qkv[tokb + 1536 + d0];
      unsigned qin[4] = {qv.x, qv.y, qv.z, qv.w};
      unsigned kin[4] = {kv.x, kv.y, kv.z, kv.w};
      unsigned qo[4], ko[4];
#pragma unroll
      for (int j = 0; j < 4; ++j){
        float2 cssn = rp[r * 32 + (d0 >> 1) + j];
        float cs = cssn.x, sn = cssn.y;
        float qe = blo(qin[j]), qd = bhi(qin[j]);
        float ke = blo(kin[j]), kd = bhi(kin[j]);
        qo[j] = (unsigned)f2b(qe * cs - qd * sn) | ((unsigned)f2b(qe * sn + qd * cs) << 16);
        ko[j] = (unsigned)f2b(ke * cs - kd * sn) | ((unsigned)f2b(ke * sn + kd * cs) << 16);
      }
      const int byq = r * 128 + ((d0 * 2) ^ ((r & 7) << 4));
      *(uint4*)((char*)Qs + byq) = make_uint4(qo[0], qo[1], qo[2], qo[3]);
      *(uint4*)((char*)Ks + byq) = make_uint4(ko[0], ko[1], ko[2], ko[3]);
      unsigned vin[4] = {vv.x, vv.y, vv.z, vv.w};
#pragma unroll
      for (int j = 0; j < 8; ++j){
        const int d = d0 + j;
        unsigned short val = (j & 1) ? (unsigned short)(vin[j >> 1] >> 16)
                                     : (unsigned short)(vin[j >> 1] & 0xffffu);
        *(unsigned short*)((char*)Vt + d * 256 + ((r * 2) ^ ((d & 7) << 4))) = val;
      }
    }
  }
  __syncthreads();

  const int qbase = w * 32;
  f32x4 st[8][2];
#pragma unroll
  for (int i = 0; i < 8; ++i){ st[i][0] = f32x4{0.f,0.f,0.f,0.f}; st[i][1] = f32x4{0.f,0.f,0.f,0.f}; }
#pragma unroll
  for (int kd = 0; kd < 2; ++kd){
    short8 bq[2];
#pragma unroll
    for (int fq = 0; fq < 2; ++fq){
      const int qr = qbase + fq * 16 + llo;
      bq[fq] = *(const short8*)((const char*)Qs + qr * 128 + ((kd * 64 + lhi * 16) ^ ((qr & 7) << 4)));
    }
#pragma unroll
    for (int fk = 0; fk < 8; ++fk){
      const int kr = fk * 16 + llo;
      short8 ak = *(const short8*)((const char*)Ks + kr * 128 + ((kd * 64 + lhi * 16) ^ ((kr & 7) << 4)));
      st[fk][0] = __builtin_amdgcn_mfma_f32_16x16x32_bf16(ak, bq[0], st[fk][0], 0, 0, 0);
      st[fk][1] = __builtin_amdgcn_mfma_f32_16x16x32_bf16(ak, bq[1], st[fk][1], 0, 0, 0);
    }
  }

#pragma unroll
  for (int fq = 0; fq < 2; ++fq){
    const int qg = qbase + fq * 16 + llo;
    float m = -1e30f;
#pragma unroll
    for (int fk = 0; fk < 8; ++fk)
#pragma unroll
      for (int rr = 0; rr < 4; ++rr){
        const int kg = fk * 16 + lhi * 4 + rr;
        float sv = (kg <= qg) ? st[fk][fq][rr] : -1e30f;
        st[fk][fq][rr] = sv;
        m = fmaxf(m, sv);
      }
    m = fmaxf(m, __shfl_xor(m, 16, 64));
    m = fmaxf(m, __shfl_xor(m, 32, 64));
    float su = 0.f;
#pragma unroll
    for (int fk = 0; fk < 8; ++fk)
#pragma unroll
      for (int rr = 0; rr < 4; ++rr){
        float p = __expf((st[fk][fq][rr] - m) * 0.125f);
        st[fk][fq][rr] = p;
        su += p;
      }
    su += __shfl_xor(su, 16, 64);
    su += __shfl_xor(su, 32, 64);
    const float rs = 1.0f / su;
#pragma unroll
    for (int fk = 0; fk < 8; ++fk){
      const int kk = fk * 16 + lhi * 4;
      unsigned lo = (unsigned)f2b(st[fk][fq][0] * rs) | ((unsigned)f2b(st[fk][fq][1] * rs) << 16);
      unsigned hi = (unsigned)f2b(st[fk][fq][2] * rs) | ((unsigned)f2b(st[fk][fq][3] * rs) << 16);
      *(uint2*)((char*)P + qg * 256 + ((kk * 2) ^ ((qg & 7) << 4))) = make_uint2(lo, hi);
    }
  }
  __syncthreads();

  f32x4 oacc[2][4];
#pragma unroll
  for (int i = 0; i < 2; ++i)
#pragma unroll
    for (int j = 0; j < 4; ++j) oacc[i][j] = f32x4{0.f,0.f,0.f,0.f};
#pragma unroll
  for (int ks = 0; ks < 4; ++ks){
    short8 pa[2];
#pragma unroll
    for (int fq = 0; fq < 2; ++fq){
      const int qr = qbase + fq * 16 + llo;
      pa[fq] = *(const short8*)((const char*)P + qr * 256 + ((ks * 64 + lhi * 16) ^ ((qr & 7) << 4)));
    }
#pragma unroll
    for (int fd = 0; fd < 4; ++fd){
      const int dr = fd * 16 + llo;
      short8 vb = *(const short8*)((const char*)Vt + dr * 256 + ((ks * 64 + lhi * 16) ^ ((dr & 7) << 4)));
      oacc[0][fd] = __builtin_amdgcn_mfma_f32_16x16x32_bf16(pa[0], vb, oacc[0][fd], 0, 0, 0);
      oacc[1][fd] = __builtin_amdgcn_mfma_f32_16x16x32_bf16(pa[1], vb, oacc[1][fd], 0, 0, 0);
    }
  }

#pragma unroll
  for (int fq = 0; fq < 2; ++fq)
#pragma unroll
    for (int fd = 0; fd < 4; ++fd)
#pragma unroll
      for (int rr = 0; rr < 4; ++rr){
        const int qg = qbase + fq * 16 + lhi * 4 + rr;
        const int d = fd * 16 + llo;
        const size_t ob = ((size_t)((b * 128 + qg) * 16 + s)) * 768 + h * 64 + d;
        o[ob] = f2b(oacc[fq][fd][rr]);
      }
}

__global__ __launch_bounds__(256) void sentinel_k(float* out){
  if (blockIdx.x == 0 && threadIdx.x == 0) out[0] = 12345.0f;
}

// ---------------- launch ----------------
extern "C" void kernel_launch(void* const* d_in, const int* in_sizes, int n_in,
                              void* d_out, int out_size, void* d_ws, size_t ws_size,
                              hipStream_t stream){
  const float* x       = (const float*)d_in[0];
  const float* sn_g    = (const float*)d_in[2];
  const float* sn_b    = (const float*)d_in[3];
  const float* sa_in_w = (const float*)d_in[4];
  const float* sa_in_b = (const float*)d_in[5];
  const float* sa_out_w= (const float*)d_in[6];
  const float* sa_out_b= (const float*)d_in[7];
  const float* tn_g    = (const float*)d_in[8];
  const float* tn_b    = (const float*)d_in[9];
  const float* tq_w    = (const float*)d_in[10];
  const float* tq_b    = (const float*)d_in[11];
  const float* tk_w    = (const float*)d_in[12];
  const float* tk_b    = (const float*)d_in[13];
  const float* tv_w    = (const float*)d_in[14];
  const float* tv_b    = (const float*)d_in[15];
  const float* to_w    = (const float*)d_in[16];
  const float* to_b    = (const float*)d_in[17];
  const float* fn_g    = (const float*)d_in[18];
  const float* fn_b    = (const float*)d_in[19];
  const float* f1_w    = (const float*)d_in[20];
  const float* f1_b    = (const float*)d_in[21];
  const float* f2_w    = (const float*)d_in[22];
  const float* f2_b    = (const float*)d_in[23];

  char* ws = (char*)d_ws;
  size_t off = 0;
  auto alloc = [&](size_t bytes) -> void* {
    void* p = ws + off;
    off += (bytes + 255) & ~(size_t)255;
    return p;
  };
  unsigned short* Wqkv = (unsigned short*)alloc((size_t)2304*768*2);
  unsigned short* Wo1  = (unsigned short*)alloc((size_t)768*768*2);
  unsigned short* W3   = (unsigned short*)alloc((size_t)2304*768*2);
  float*          b3   = (float*)alloc(2304*4);
  unsigned short* Wto  = (unsigned short*)alloc((size_t)768*768*2);
  unsigned short* Wf1  = (unsigned short*)alloc((size_t)3072*768*2);
  unsigned short* Wf2  = (unsigned short*)alloc((size_t)768*3072*2);
  float*          rope = (float*)alloc(128*32*2*4);
  unsigned short* xn   = (unsigned short*)alloc((size_t)NTOK*768*2);
  unsigned short* qkv  = (unsigned short*)alloc((size_t)NTOK*3072*2);
  unsigned short* xs2  = (unsigned short*)alloc((size_t)NTOK*768*2);
  unsigned short* xt2  = (unsigned short*)alloc((size_t)NTOK*768*2);
  unsigned short* ob   = xn; // alias: xn dead when attn output written

  if (ws_size < off){ sentinel_k<<<1, 64, 0, stream>>>((float*)d_out); return; }

  convertall_k<<<2048, 256, 0, stream>>>(sa_in_w, sa_out_w, tq_w, tk_w, tv_w, to_w, f1_w, f2_w,
                                         Wqkv, Wo1, W3, W3 + 768*768, W3 + 2*768*768, Wto, Wf1, Wf2);
  concat3_k<<<3, 256, 0, stream>>>(tq_b, tk_b, tv_b, b3);
  rope_k<<<16, 256, 0, stream>>>(rope);

  // spatial block
  ln_k<1><<<NTOK, 256, 0, stream>>>(x, sn_g, sn_b, xn);
  gemm97_k<0><<<dim3(18, 256), 256, 0, stream>>>(xn, Wqkv, sa_in_b, nullptr, qkv, 768, 2304);
  sattn_k<<<dim3(2048, 12), 256, 0, stream>>>(qkv, ob);
  gemm97_k<2><<<dim3(6, 256), 256, 0, stream>>>(ob, Wo1, sa_out_b, x, xs2, 768, 768);

  // temporal block
  ln_k<0><<<NTOK, 256, 0, stream>>>(xs2, tn_g, tn_b, xn);
  gemm97_k<0><<<dim3(18, 256), 256, 0, stream>>>(xn, W3, b3, nullptr, qkv, 768, 2304);
  tattn_k<<<dim3(256, 12), 256, 0, stream>>>(qkv, rope, ob);
  gemm97_k<3><<<dim3(6, 256), 256, 0, stream>>>(ob, Wto, to_b, xs2, xt2, 768, 768);

  // FFN
  ln_k<0><<<NTOK, 256, 0, stream>>>(xt2, fn_g, fn_b, xn);
  gemm97_k<1><<<dim3(24, 256), 256, 0, stream>>>(xn, Wf1, f1_b, nullptr, qkv, 768, 3072);
  gemm97_k<4><<<dim3(6, 256), 256, 0, stream>>>(qkv, Wf2, f2_b, xt2, d_out, 3072, 768);
}